// Round 1
// baseline (5766.499 us; speedup 1.0000x reference)
//
#include <hip/hip_runtime.h>
#include <stdint.h>

#define TT 2560
#define BB 64
#define CC 22
#define CP 24

typedef unsigned short ushort_t;
typedef __attribute__((ext_vector_type(4))) float floatx4;
typedef __attribute__((ext_vector_type(8))) short bf16x8;

__device__ __forceinline__ float bf2f(ushort_t u){
  union { uint32_t i; float f; } v; v.i = ((uint32_t)u) << 16; return v.f;
}
__device__ __forceinline__ ushort_t f2bf(float f){
  union { float f; uint32_t i; } v; v.f = f;
  uint32_t r = v.i + 0x7FFFu + ((v.i >> 16) & 1u);
  return (ushort_t)(r >> 16);
}
__device__ __forceinline__ float sigmoidf_(float x){ return 1.f/(1.f + __expf(-x)); }
__device__ __forceinline__ float tanhf_(float x){ return 2.f/(1.f + __expf(-2.f*x)) - 1.f; }

// ---------------- K0a: transpose x [B][C][T] -> xT [B][T][CP] (pad c=22,23 with 0)
__global__ __launch_bounds__(256) void k_transpose_x(const float* __restrict__ x, float* __restrict__ xT){
  int idx = blockIdx.x*256 + threadIdx.x;           // 0 .. B*T-1
  if (idx >= BB*TT) return;
  int b = idx / TT, t = idx % TT;
  float* dst = xT + (size_t)idx*CP;
  const float* src = x + (size_t)b*CC*TT + t;
  #pragma unroll
  for (int c=0;c<CC;c++) dst[c] = src[(size_t)c*TT];
  dst[22] = 0.f; dst[23] = 0.f;
}

// ---------------- K0b: WxT1[dir][n][k] = bf16(Wx1[dir][k][n])  (256x256 each)
__global__ __launch_bounds__(256) void k_prep_wxT(const float* __restrict__ Wf, const float* __restrict__ Wb,
                                                  ushort_t* __restrict__ WT){
  int idx = blockIdx.x*256 + threadIdx.x;           // 0 .. 2*65536-1
  int dir = idx >> 16; int r = idx & 65535; int n = r >> 8; int k = r & 255;
  const float* W = dir ? Wb : Wf;
  WT[idx] = f2bf(W[k*256 + n]);
}

// ---------------- K1: layer-0 scan. 1 chain (batch,dir) per WG, 512 threads.
// Thread j owns column j of Wh0 (128 fp32 regs) + column j of Wx0 (22 regs) + bias.
__global__ __launch_bounds__(512, 2) void k_lstm0(
  const float* __restrict__ xT,
  const float* __restrict__ WxF, const float* __restrict__ WhF, const float* __restrict__ bF,
  const float* __restrict__ WxB, const float* __restrict__ WhB, const float* __restrict__ bB,
  ushort_t* __restrict__ h0seq)                     // [B][T][256] bf16, fwd at +0, bwd at +128
{
  const int chain = blockIdx.x;
  const int dir = chain & 1;
  const int b = chain >> 1;
  const float* Wx = dir ? WxB : WxF;
  const float* Wh = dir ? WhB : WhF;
  const float* bi = dir ? bB  : bF;
  const int j = threadIdx.x;

  float wh[128];
  #pragma unroll
  for (int k=0;k<128;k++) wh[k] = Wh[k*512 + j];
  float wx[CC];
  #pragma unroll
  for (int c=0;c<CC;c++) wx[c] = Wx[c*512 + j];
  const float bj = bi[j];

  __shared__ __align__(16) float h_lds[128];
  __shared__ __align__(16) float z_lds[512];
  __shared__ __align__(16) float x_lds[2][CP];

  float cst = 0.f;
  if (j < 128) h_lds[j] = 0.f;

  const size_t xbase = (size_t)b*TT*CP;
  float xreg = 0.f;
  {
    int s0 = 0, s1 = 1;
    int t0 = dir ? (TT-1-s0) : s0;
    int t1 = dir ? (TT-1-s1) : s1;
    if (j >= 128 && j < 128+CC){
      int c = j - 128;
      x_lds[0][c] = xT[xbase + (size_t)t0*CP + c];
      xreg        = xT[xbase + (size_t)t1*CP + c];
    }
  }
  __syncthreads();

  const size_t hbase = (size_t)b*TT*256 + (size_t)dir*128;
  for (int s = 0; s < TT; ++s){
    const float* xc = x_lds[s & 1];
    float a0 = bj, a1 = 0.f, a2 = 0.f, a3 = 0.f;
    #pragma unroll
    for (int c=0;c<20;c+=4){
      float4 xv = *(const float4*)&xc[c];
      a0 += xv.x*wx[c]; a1 += xv.y*wx[c+1]; a2 += xv.z*wx[c+2]; a3 += xv.w*wx[c+3];
    }
    a0 += xc[20]*wx[20]; a1 += xc[21]*wx[21];
    #pragma unroll
    for (int k=0;k<128;k+=4){
      float4 hv = *(const float4*)&h_lds[k];
      a0 += hv.x*wh[k]; a1 += hv.y*wh[k+1]; a2 += hv.z*wh[k+2]; a3 += hv.w*wh[k+3];
    }
    z_lds[j] = (a0+a1)+(a2+a3);
    __syncthreads();
    if (j < 128){
      float zi = z_lds[j], zf = z_lds[128+j], zg = z_lds[256+j], zo = z_lds[384+j];
      float ig = sigmoidf_(zi), fg = sigmoidf_(zf), gg = tanhf_(zg), og = sigmoidf_(zo);
      cst = fg*cst + ig*gg;
      float h = og * tanhf_(cst);
      h_lds[j] = h;
      int t = dir ? (TT-1-s) : s;
      h0seq[hbase + (size_t)t*256 + j] = f2bf(h);
    } else if (j < 128+CC){
      int c = j - 128;
      x_lds[(s+1)&1][c] = xreg;
      int sn = s + 2; if (sn > TT-1) sn = TT-1;
      int tn = dir ? (TT-1-sn) : sn;
      xreg = xT[xbase + (size_t)tn*CP + c];
    }
    __syncthreads();
  }
}

// ---------------- K2: xz1[dir][bt][256] = bf16( h0seq[bt][:256] @ Wx1[dir] ), bf16 MFMA, LDS-free.
// WG = M128 x N256, 8 waves: wave tile M32 x N128 (2 m-tiles x 8 n-tiles of 16x16).
__global__ __launch_bounds__(512) void k_xz1_gemm(const ushort_t* __restrict__ h0seq,
                                                  const ushort_t* __restrict__ WxT,   // [dir][n=256][k=256]
                                                  ushort_t* __restrict__ xz1)
{
  const int mb  = blockIdx.x;     // 0..1279
  const int dir = blockIdx.y;     // 0..1
  const ushort_t* W   = WxT + (size_t)dir*256*256;
  ushort_t*       out = xz1 + (size_t)dir*BB*TT*256;
  const int wave = threadIdx.x >> 6;
  const int lane = threadIdx.x & 63;
  const int mw = wave & 3;        // rows mb*128 + mw*32
  const int nw = wave >> 2;       // cols nw*128
  const int m_ = lane & 15;
  const int q_ = lane >> 4;

  floatx4 acc[2][8];
  #pragma unroll
  for (int a=0;a<2;a++)
    #pragma unroll
    for (int n=0;n<8;n++) acc[a][n] = (floatx4)0.f;

  const size_t Abase = ((size_t)mb*128 + mw*32 + m_)*256 + q_*8;
  const size_t Bbase = ((size_t)nw*128 + m_)*256 + q_*8;

  for (int kc = 0; kc < 256; kc += 32){
    bf16x8 afr[2];
    #pragma unroll
    for (int mt=0;mt<2;mt++)
      afr[mt] = *(const bf16x8*)(h0seq + Abase + (size_t)mt*16*256 + kc);
    #pragma unroll
    for (int nt=0;nt<8;nt++){
      bf16x8 bfr = *(const bf16x8*)(W + Bbase + (size_t)nt*16*256 + kc);
      #pragma unroll
      for (int mt=0;mt<2;mt++)
        acc[mt][nt] = __builtin_amdgcn_mfma_f32_16x16x32_bf16(afr[mt], bfr, acc[mt][nt], 0,0,0);
    }
  }
  #pragma unroll
  for (int mt=0;mt<2;mt++)
    #pragma unroll
    for (int nt=0;nt<8;nt++)
      #pragma unroll
      for (int r=0;r<4;r++){
        size_t row = (size_t)mb*128 + mw*32 + mt*16 + q_*4 + r;
        int    col = nw*128 + nt*16 + m_;
        out[row*256 + col] = f2bf(acc[mt][nt][r]);
      }
}

// ---------------- K3: layer-1 scan (keeps only final h). 1 chain per WG, 256 threads.
__global__ __launch_bounds__(256) void k_lstm1(
  const ushort_t* __restrict__ xz1,                 // [2][B][T][256] bf16
  const float* __restrict__ WhF, const float* __restrict__ bF,
  const float* __restrict__ WhB, const float* __restrict__ bB,
  float* __restrict__ h1last)                       // [B][128]: fwd 0..63, bwd 64..127
{
  const int chain = blockIdx.x;
  const int dir = chain & 1;
  const int b = chain >> 1;
  const ushort_t* XZ = xz1 + (size_t)dir*BB*TT*256;
  const float* Wh = dir ? WhB : WhF;
  const float* bi = dir ? bB  : bF;
  const int j = threadIdx.x;

  float wh[64];
  #pragma unroll
  for (int k=0;k<64;k++) wh[k] = Wh[k*256 + j];
  const float bj = bi[j];

  __shared__ __align__(16) float h_lds[64];
  __shared__ __align__(16) float z_lds[256];
  float cst = 0.f;
  float hlast = 0.f;
  if (j < 64) h_lds[j] = 0.f;

  const size_t base = (size_t)b*TT*256 + j;
  ushort_t p0, p1, p2;
  {
    int t0 = dir ? (TT-1) : 0;
    int t1 = dir ? (TT-2) : 1;
    int t2 = dir ? (TT-3) : 2;
    p0 = XZ[base + (size_t)t0*256];
    p1 = XZ[base + (size_t)t1*256];
    p2 = XZ[base + (size_t)t2*256];
  }
  __syncthreads();

  for (int s = 0; s < TT; ++s){
    float a0 = bj + bf2f(p0), a1=0.f, a2=0.f, a3=0.f;
    p0 = p1; p1 = p2;
    { int sn = s + 3; if (sn > TT-1) sn = TT-1;
      int tn = dir ? (TT-1-sn) : sn;
      p2 = XZ[base + (size_t)tn*256]; }
    #pragma unroll
    for (int k=0;k<64;k+=4){
      float4 hv = *(const float4*)&h_lds[k];
      a0 += hv.x*wh[k]; a1 += hv.y*wh[k+1]; a2 += hv.z*wh[k+2]; a3 += hv.w*wh[k+3];
    }
    z_lds[j] = (a0+a1)+(a2+a3);
    __syncthreads();
    if (j < 64){
      float zi = z_lds[j], zf = z_lds[64+j], zg = z_lds[128+j], zo = z_lds[192+j];
      float ig = sigmoidf_(zi), fg = sigmoidf_(zf), gg = tanhf_(zg), og = sigmoidf_(zo);
      cst = fg*cst + ig*gg;
      hlast = og * tanhf_(cst);
      h_lds[j] = hlast;
    }
    __syncthreads();
  }
  if (j < 64) h1last[b*128 + dir*64 + j] = hlast;
}

// ---------------- K4: dense head, one WG per batch row.
__global__ __launch_bounds__(128) void k_head(
  const float* __restrict__ h1last,
  const float* __restrict__ d0W, const float* __restrict__ d0b,
  const float* __restrict__ d1W, const float* __restrict__ d1b,
  const float* __restrict__ oW,  const float* __restrict__ ob,
  float* __restrict__ outp)
{
  const int b = blockIdx.x;
  const int j = threadIdx.x;
  __shared__ float v0[128], v1[128];
  v0[j] = h1last[b*128 + j];
  __syncthreads();
  float acc = d0b[j];
  #pragma unroll
  for (int k=0;k<128;k++) acc += v0[k]*d0W[k*128 + j];
  v1[j] = fmaxf(acc, 0.f);
  __syncthreads();
  if (j < 64){
    float a2 = d1b[j];
    #pragma unroll
    for (int k=0;k<128;k++) a2 += v1[k]*d1W[k*64 + j];
    float p = fmaxf(a2, 0.f) * oW[j];
    #pragma unroll
    for (int off=32; off>0; off>>=1) p += __shfl_down(p, off, 64);
    if (j == 0) outp[b] = 1.f/(1.f + __expf(-(p + ob[0])));
  }
}

extern "C" void kernel_launch(void* const* d_in, const int* in_sizes, int n_in,
                              void* d_out, int out_size, void* d_ws, size_t ws_size,
                              hipStream_t stream)
{
  const float* x     = (const float*)d_in[0];
  const float* l0fWx = (const float*)d_in[1];
  const float* l0fWh = (const float*)d_in[2];
  const float* l0fb  = (const float*)d_in[3];
  const float* l0bWx = (const float*)d_in[4];
  const float* l0bWh = (const float*)d_in[5];
  const float* l0bb  = (const float*)d_in[6];
  const float* l1fWx = (const float*)d_in[7];
  const float* l1fWh = (const float*)d_in[8];
  const float* l1fb  = (const float*)d_in[9];
  const float* l1bWx = (const float*)d_in[10];
  const float* l1bWh = (const float*)d_in[11];
  const float* l1bb  = (const float*)d_in[12];
  const float* d0W = (const float*)d_in[13];
  const float* d0b = (const float*)d_in[14];
  const float* d1W = (const float*)d_in[15];
  const float* d1b = (const float*)d_in[16];
  const float* oW  = (const float*)d_in[17];
  const float* ob  = (const float*)d_in[18];
  float* outp = (float*)d_out;

  char* ws = (char*)d_ws;
  const size_t OFF_XT  = 0;                        // 64*2560*24*4   = 15,728,640
  const size_t OFF_H0  = OFF_XT  + 15728640ull;    // 64*2560*256*2  = 83,886,080
  const size_t OFF_XZ  = OFF_H0  + 83886080ull;    // 2*64*2560*256*2= 167,772,160
  const size_t OFF_WT  = OFF_XZ  + 167772160ull;   // 2*256*256*2    = 262,144
  const size_t OFF_H1  = OFF_WT  + 262144ull;      // 64*128*4       = 32,768

  float*    xT  = (float*)(ws + OFF_XT);
  ushort_t* h0  = (ushort_t*)(ws + OFF_H0);
  ushort_t* xz1 = (ushort_t*)(ws + OFF_XZ);
  ushort_t* WT  = (ushort_t*)(ws + OFF_WT);
  float*    h1l = (float*)(ws + OFF_H1);

  hipLaunchKernelGGL(k_transpose_x, dim3(640), dim3(256), 0, stream, x, xT);
  hipLaunchKernelGGL(k_prep_wxT,    dim3(512), dim3(256), 0, stream, l1fWx, l1bWx, WT);
  hipLaunchKernelGGL(k_lstm0,       dim3(128), dim3(512), 0, stream,
                     xT, l0fWx, l0fWh, l0fb, l0bWx, l0bWh, l0bb, h0);
  hipLaunchKernelGGL(k_xz1_gemm,    dim3(1280,2), dim3(512), 0, stream, h0, WT, xz1);
  hipLaunchKernelGGL(k_lstm1,       dim3(128), dim3(256), 0, stream,
                     xz1, l1fWh, l1fb, l1bWh, l1bb, h1l);
  hipLaunchKernelGGL(k_head,        dim3(64), dim3(128), 0, stream,
                     h1l, d0W, d0b, d1W, d1b, oW, ob, outp);
}